// Round 9
// baseline (995.752 us; speedup 1.0000x reference)
//
#include <hip/hip_runtime.h>
#include <cstdint>
#include <cstddef>

// Problem constants
#define NB 256
#define SQ 500
#define NROWS (NB * SQ)   // 128000
#define DQ 128
#define DV 256
#define MM 50
#define FF 512
#define WSTRIDE 64        // padded w-row stride (cols 50..63 zero)

typedef _Float16 half8 __attribute__((ext_vector_type(8)));
typedef float floatx4 __attribute__((ext_vector_type(4)));
typedef unsigned short u16;
typedef unsigned int u32;

__device__ __forceinline__ float4 ld4(const float* p) {
    return *reinterpret_cast<const float4*>(p);
}
__device__ __forceinline__ float sigf(float x) { return 1.f / (1.f + __expf(-x)); }
__device__ __forceinline__ float tanhfast(float x) { return 2.f / (1.f + __expf(-2.f * x)) - 1.f; }
__device__ __forceinline__ int gmap(int l, int s0, int CS) {
    int b = (unsigned)l / (unsigned)CS;
    return b * SQ + s0 + (l - b * CS);
}
__device__ __forceinline__ void st4h(u16* dst, float4 v) {
    _Float16 h0 = (_Float16)v.x, h1 = (_Float16)v.y, h2 = (_Float16)v.z, h3 = (_Float16)v.w;
    ushort4 u;
    u.x = *(u16*)&h0; u.y = *(u16*)&h1; u.z = *(u16*)&h2; u.w = *(u16*)&h3;
    *(ushort4*)dst = u;
}
__device__ __forceinline__ float h2f(u16 b) { _Float16 h; *(u16*)&h = b; return (float)h; }
__device__ __forceinline__ u16 f2h(float x) { _Float16 h = (_Float16)x; return *(u16*)&h; }

// ---------------------------------------------------------------------------
// fp32 -> fp16 conversion (vec4)
// ---------------------------------------------------------------------------
__global__ __launch_bounds__(256) void cvt16(
    const float* __restrict__ s, u16* __restrict__ d, int n4)
{
    int i = blockIdx.x * 256 + threadIdx.x;
    if (i < n4) st4h(d + 4 * (size_t)i, ld4(s + 4 * (size_t)i));
}

// ---------------------------------------------------------------------------
// Mk [50,128] fp32 -> Mkh [64,128] fp16, rows 50..63 zeroed
// ---------------------------------------------------------------------------
__global__ __launch_bounds__(256) void mkcvt(
    const float* __restrict__ Mk, u16* __restrict__ Mkh)
{
    int i = blockIdx.x * 256 + threadIdx.x;   // 2048 float4 slots
    if (i >= 64 * 32) return;
    int row = i >> 5;
    float4 v = (row < MM) ? ld4(Mk + (size_t)row * DQ + (i & 31) * 4)
                          : float4{0.f, 0.f, 0.f, 0.f};
    st4h(Mkh + 4 * (size_t)i, v);
}

// ---------------------------------------------------------------------------
// prep: Xp rows [0,Nc) = fp16(te+qe); rows [Nc,2Nc) = fp16(he+hte+ae+qe);
//       S3p = fp16(he+hte+ae); QEp = fp16(qe)
// ---------------------------------------------------------------------------
__global__ __launch_bounds__(256) void prep128(
    const int* __restrict__ q_data, const int* __restrict__ time_data,
    const int* __restrict__ attempt_data, const int* __restrict__ hint_data,
    const int* __restrict__ hintT_data,
    const float* __restrict__ q_emb, const float* __restrict__ time_emb,
    const float* __restrict__ attempt_emb, const float* __restrict__ ht_emb,
    u16* __restrict__ Xp, u16* __restrict__ S3p, u16* __restrict__ QEp,
    int s0, int CS, int Nc)
{
    int g = blockIdx.x * 256 + threadIdx.x;
    int l = g >> 5;
    int kq = (g & 31) << 2;
    if (l >= Nc) return;
    int n = gmap(l, s0, CS);
    float4 qe  = ld4(q_emb       + (size_t)q_data[n]       * DQ + kq);
    float4 te  = ld4(time_emb    + (size_t)time_data[n]    * DQ + kq);
    float4 ae  = ld4(attempt_emb + (size_t)attempt_data[n] * DQ + kq);
    float4 he  = ld4(ht_emb      + (size_t)hint_data[n]    * DQ + kq);
    float4 hte = ld4(ht_emb      + (size_t)hintT_data[n]   * DQ + kq);
    size_t off = (size_t)l * DQ + kq;
    float4 x1, s3, x2;
    x1.x = te.x + qe.x; x1.y = te.y + qe.y; x1.z = te.z + qe.z; x1.w = te.w + qe.w;
    s3.x = he.x + hte.x + ae.x; s3.y = he.y + hte.y + ae.y;
    s3.z = he.z + hte.z + ae.z; s3.w = he.w + hte.w + ae.w;
    x2.x = s3.x + qe.x; x2.y = s3.y + qe.y; x2.z = s3.z + qe.z; x2.w = s3.w + qe.w;
    st4h(Xp + off, x1);
    st4h(Xp + (size_t)Nc * DQ + off, x2);
    st4h(S3p + off, s3);
    st4h(QEp + off, qe);
}

// ---------------------------------------------------------------------------
// fp16 MFMA GEMM: Y = epi(act(A @ W^T + bias)), BM=BN=128, BK=32, 4 waves,
// wave tile 64x64 = 4x4 of v_mfma_f32_16x16x32_f16.
// MODE 1: tanh -> fp16 Yh (stride 128)               [lin1 on 2Nc rows]
// MODE 2: sig; row<Nc: tf->Yh; row>=Nc: x3=qe+v*s3 -> Yh  [lin2 batched]
// MODE 3: none; qp->Yh; fused ie=qp+tf*te -> AUX[,256:384] [lin1(X3)+ew_ie]
// MODE 4: gather A=qaE[idx]; by<2: sig->e, else tanh->a; packed u16 pairs->AUX
// MODE 5: tanh(rc); pred-partial reduce -> atomicAdd Yf    [readout+pred]
// ---------------------------------------------------------------------------
template <int MODE>
__global__ __launch_bounds__(256, 3) void gemm16(
    const u16* __restrict__ A, const u16* __restrict__ W0,
    const u16* __restrict__ W1, const float* __restrict__ b0,
    const float* __restrict__ b1, u16* __restrict__ Yh,
    float* __restrict__ Yf,
    const u16* __restrict__ QEp, const u16* __restrict__ S3p,
    const int* __restrict__ idx, const float* __restrict__ gtab,
    u16* __restrict__ AUX, const float* __restrict__ predW,
    int K, int Nc, int s0, int CS)
{
    __shared__ u16 smem[2 * 128 * 40];   // 20480 B: A-tile | B-tile (pitch 80B)
    u16* At = smem;
    u16* Bt = smem + 128 * 40;
    const int tid = threadIdx.x;
    const int row0 = blockIdx.x * 128;
    const int by = blockIdx.y;

    const u16* Wp;
    int col0;
    if constexpr (MODE == 4) { Wp = (by < 2) ? W0 : W1; col0 = (by & 1) * 128; }
    else { Wp = W0; col0 = by * 128; }
    const float* bias = (MODE == 4 && by >= 2) ? b1 : b0;

    floatx4 acc[4][4];
#pragma unroll
    for (int m = 0; m < 4; ++m)
#pragma unroll
        for (int n = 0; n < 4; ++n) acc[m][n] = (floatx4)0.f;

    const int lane = tid & 63, wv = tid >> 6;
    const int wr = (wv >> 1) * 64, wc = (wv & 1) * 64;
    const int q = lane >> 4, c0 = lane & 15;

    for (int kt = 0; kt < K; kt += 32) {
#pragma unroll
        for (int i = 0; i < 4; ++i) {
            int c = tid + i * 256;          // [0,1024)
            if (c < 512) {
                int r = c >> 2, seg = c & 3;
                const u16* src;
                if constexpr (MODE == 4) {
                    int g = idx[gmap(row0 + r, s0, CS)];
                    src = A + (size_t)g * K + kt + seg * 8;
                } else {
                    src = A + (size_t)(row0 + r) * K + kt + seg * 8;
                }
                *(uint4*)&At[r * 40 + seg * 8] = *(const uint4*)src;
            } else {
                int cb = c - 512;
                int r = cb >> 2, seg = cb & 3;
                const u16* src = Wp + (size_t)(col0 + r) * K + kt + seg * 8;
                *(uint4*)&Bt[r * 40 + seg * 8] = *(const uint4*)src;
            }
        }
        __syncthreads();
        half8 af[4], bf[4];
#pragma unroll
        for (int m = 0; m < 4; ++m) af[m] = *(half8*)&At[(wr + m * 16 + c0) * 40 + q * 8];
#pragma unroll
        for (int n = 0; n < 4; ++n) bf[n] = *(half8*)&Bt[(wc + n * 16 + c0) * 40 + q * 8];
#pragma unroll
        for (int m = 0; m < 4; ++m)
#pragma unroll
            for (int n = 0; n < 4; ++n)
                acc[m][n] = __builtin_amdgcn_mfma_f32_16x16x32_f16(af[m], bf[n], acc[m][n], 0, 0, 0);
        __syncthreads();
    }

    float bv[4];
#pragma unroll
    for (int n = 0; n < 4; ++n) bv[n] = bias[col0 + wc + n * 16 + c0];

    if constexpr (MODE == 5) {
        float pw[4];
#pragma unroll
        for (int n = 0; n < 4; ++n) pw[n] = predW[col0 + wc + n * 16 + c0];
        float* red = (float*)smem;          // [128][33] = 16896 B <= 20480
#pragma unroll
        for (int m = 0; m < 4; ++m)
#pragma unroll
            for (int r4 = 0; r4 < 4; ++r4) {
                int row = wr + m * 16 + q * 4 + r4;
                float pp = 0.f;
#pragma unroll
                for (int n = 0; n < 4; ++n)
                    pp = fmaf(tanhfast(acc[m][n][r4] + bv[n]), pw[n], pp);
                red[row * 33 + (wv & 1) * 16 + c0] = pp;
            }
        __syncthreads();
        if (tid < 128) {
            float s = 0.f;
#pragma unroll
            for (int j = 0; j < 32; ++j) s += red[tid * 33 + j];
            atomicAdd(&Yf[row0 + tid], s);
        }
    } else {
#pragma unroll
        for (int m = 0; m < 4; ++m)
#pragma unroll
            for (int r4 = 0; r4 < 4; ++r4) {
                int row = row0 + wr + m * 16 + q * 4 + r4;
#pragma unroll
                for (int n = 0; n < 4; ++n) {
                    int col = col0 + wc + n * 16 + c0;
                    float v = acc[m][n][r4] + bv[n];
                    if constexpr (MODE == 1) {
                        Yh[(size_t)row * 128 + col] = f2h(tanhfast(v));
                    } else if constexpr (MODE == 2) {
                        v = sigf(v);
                        if (row < Nc) {
                            Yh[(size_t)row * 128 + col] = f2h(v);
                        } else {
                            size_t o = (size_t)(row - Nc) * 128 + col;
                            float qe = h2f(QEp[o]), s3 = h2f(S3p[o]);
                            Yh[(size_t)row * 128 + col] = f2h(fmaf(v, s3, qe));
                        }
                    } else if constexpr (MODE == 3) {
                        size_t o = (size_t)row * 128 + col;
                        float tf = h2f(Yh[o]);   // read tf BEFORE overwriting with qp
                        float te = gtab[(size_t)idx[gmap(row, s0, CS)] * 128 + col];
                        AUX[(size_t)row * 384 + 256 + col] = f2h(fmaf(tf, te, v));
                        Yh[o] = f2h(v);
                    } else { // MODE 4
                        bool isE = (by < 2);
                        v = isE ? sigf(v) : tanhfast(v);
                        AUX[((size_t)row * 256 + col) * 2 + (isE ? 0 : 1)] = f2h(v);
                    }
                }
            }
    }
}

// ---------------------------------------------------------------------------
// w = softmax(qp @ Mk^T) via MFMA. Block: 128 rows x 64 cols (50 live).
// Logits -> LDS (pitch 67), row softmax, zero cols 50..63, coalesced store
// to Wb (stride WSTRIDE=64).
// ---------------------------------------------------------------------------
__global__ __launch_bounds__(256) void wsoftmax_mfma(
    const u16* __restrict__ QP, const u16* __restrict__ Mkh,
    float* __restrict__ Wb)
{
    __shared__ float Sred[128 * 67];        // 34304 B; head doubles as At/Bt
    u16* At = (u16*)Sred;                   // [128][40] fp16 = 10240 B
    u16* Bt = At + 128 * 40;                // [64][40]  fp16 =  5120 B
    const int tid = threadIdx.x;
    const int row0 = blockIdx.x * 128;
    const int lane = tid & 63, wv = tid >> 6;
    const int wr = wv * 32;                 // wave: 32 rows x 64 cols
    const int q = lane >> 4, c0 = lane & 15;

    floatx4 acc[2][4];
#pragma unroll
    for (int m = 0; m < 2; ++m)
#pragma unroll
        for (int n = 0; n < 4; ++n) acc[m][n] = (floatx4)0.f;

    for (int kt = 0; kt < DQ; kt += 32) {
#pragma unroll
        for (int i = 0; i < 3; ++i) {
            int c = tid + i * 256;          // [0,768)
            if (c < 512) {
                int r = c >> 2, seg = c & 3;
                *(uint4*)&At[r * 40 + seg * 8] =
                    *(const uint4*)(QP + (size_t)(row0 + r) * DQ + kt + seg * 8);
            } else {
                int cb = c - 512;
                int r = cb >> 2, seg = cb & 3;
                *(uint4*)&Bt[r * 40 + seg * 8] =
                    *(const uint4*)(Mkh + (size_t)r * DQ + kt + seg * 8);
            }
        }
        __syncthreads();
        half8 af[2], bf[4];
#pragma unroll
        for (int m = 0; m < 2; ++m) af[m] = *(half8*)&At[(wr + m * 16 + c0) * 40 + q * 8];
#pragma unroll
        for (int n = 0; n < 4; ++n) bf[n] = *(half8*)&Bt[(n * 16 + c0) * 40 + q * 8];
#pragma unroll
        for (int m = 0; m < 2; ++m)
#pragma unroll
            for (int n = 0; n < 4; ++n)
                acc[m][n] = __builtin_amdgcn_mfma_f32_16x16x32_f16(af[m], bf[n], acc[m][n], 0, 0, 0);
        __syncthreads();
    }

    // dump logits to LDS: row = wr + m*16 + q*4 + r, col = n*16 + c0
#pragma unroll
    for (int m = 0; m < 2; ++m)
#pragma unroll
        for (int r4 = 0; r4 < 4; ++r4) {
            int row = wr + m * 16 + q * 4 + r4;
#pragma unroll
            for (int n = 0; n < 4; ++n)
                Sred[row * 67 + n * 16 + c0] = acc[m][n][r4];
        }
    __syncthreads();

    // row-wise softmax over 50 live cols; zero pad cols 50..63
    if (tid < 128) {
        float* s = &Sred[tid * 67];
        float mx = -3.0e38f;
#pragma unroll
        for (int m = 0; m < MM; ++m) mx = fmaxf(mx, s[m]);
        float sum = 0.f;
#pragma unroll
        for (int m = 0; m < MM; ++m) { float e = __expf(s[m] - mx); s[m] = e; sum += e; }
        float inv = 1.f / sum;
#pragma unroll
        for (int m = 0; m < MM; ++m) s[m] *= inv;
#pragma unroll
        for (int m = MM; m < 64; ++m) s[m] = 0.f;
    }
    __syncthreads();

    // coalesced store: 128 rows x 16 float4
    for (int i = tid; i < 128 * 16; i += 256) {
        int row = i >> 4, seg = i & 15;
        float4 v;
        v.x = Sred[row * 67 + seg * 4 + 0];
        v.y = Sred[row * 67 + seg * 4 + 1];
        v.z = Sred[row * 67 + seg * 4 + 2];
        v.w = Sred[row * 67 + seg * 4 + 3];
        *(float4*)(Wb + (size_t)(row0 + row) * WSTRIDE + seg * 4) = v;
    }
}

// ---------------------------------------------------------------------------
// DKVMN scan v4: 256 blocks x 1024 threads, m-split 4-way (wave = 16d x 4mg).
// ALL state in NAMED float4 registers, passed by reference through
// __forceinline__ helpers (no indexed arrays -> no AGPR shuttle, no macros).
// t-loop unrolled x2 with explicit A/B register sets (zero-copy ping-pong).
// ---------------------------------------------------------------------------
__device__ __forceinline__ float dot16(
    const float4& w0, const float4& w1, const float4& w2, const float4& w3,
    const float4& m0, const float4& m1, const float4& m2, const float4& m3)
{
    float r = w0.x * m0.x;
    r = fmaf(w0.y, m0.y, r); r = fmaf(w0.z, m0.z, r); r = fmaf(w0.w, m0.w, r);
    r = fmaf(w1.x, m1.x, r); r = fmaf(w1.y, m1.y, r); r = fmaf(w1.z, m1.z, r); r = fmaf(w1.w, m1.w, r);
    r = fmaf(w2.x, m2.x, r); r = fmaf(w2.y, m2.y, r); r = fmaf(w2.z, m2.z, r); r = fmaf(w2.w, m2.w, r);
    r = fmaf(w3.x, m3.x, r); r = fmaf(w3.y, m3.y, r); r = fmaf(w3.z, m3.z, r); r = fmaf(w3.w, m3.w, r);
    return r;
}

__device__ __forceinline__ void upd4(float4& mv, const float4& wv, float e, float a)
{
    mv.x = fmaf(mv.x, fmaf(-wv.x, e, 1.f), wv.x * a);
    mv.y = fmaf(mv.y, fmaf(-wv.y, e, 1.f), wv.y * a);
    mv.z = fmaf(mv.z, fmaf(-wv.z, e, 1.f), wv.z * a);
    mv.w = fmaf(mv.w, fmaf(-wv.w, e, 1.f), wv.w * a);
}

__device__ __forceinline__ void scan_step(
    const float4& w0, const float4& w1, const float4& w2, const float4& w3,
    u32 eav, int mg, u16* rp,
    float4& mv0, float4& mv1, float4& mv2, float4& mv3)
{
    const float e = h2f((u16)(eav & 0xffff));
    const float a = h2f((u16)(eav >> 16));
    float r = dot16(w0, w1, w2, w3, mv0, mv1, mv2, mv3);
    r += __shfl_xor(r, 16);
    r += __shfl_xor(r, 32);
    if (mg == 0) *rp = f2h(r);
    upd4(mv0, w0, e, a);
    upd4(mv1, w1, e, a);
    upd4(mv2, w2, e, a);
    upd4(mv3, w3, e, a);
}

__global__ __launch_bounds__(1024, 4) void scan_kernel(
    const float* __restrict__ Wb, const u32* __restrict__ EA,
    const float* __restrict__ Mv0, float* __restrict__ MvSt,
    u16* __restrict__ RDIE, int CS, int first)
{
    const int b = blockIdx.x;
    const int tid = threadIdx.x;
    const int lane = tid & 63;
    const int wave = tid >> 6;
    const int mg = lane >> 4;        // 0..3
    const int dl = lane & 15;
    const int d = wave * 16 + dl;    // 0..255
    const int m0 = mg * 16;

    float4 mv0, mv1, mv2, mv3;
    {
        float t0[16];
#pragma unroll
        for (int j = 0; j < 16; ++j) {
            int m = m0 + j;
            t0[j] = (m < MM) ? (first ? Mv0[m * DV + d]
                                      : MvSt[((size_t)b * MM + m) * DV + d]) : 0.f;
        }
        mv0 = float4{t0[0], t0[1], t0[2], t0[3]};
        mv1 = float4{t0[4], t0[5], t0[6], t0[7]};
        mv2 = float4{t0[8], t0[9], t0[10], t0[11]};
        mv3 = float4{t0[12], t0[13], t0[14], t0[15]};
    }

    const float* wp = Wb + ((size_t)b * CS) * WSTRIDE + m0;
    const u32* ep = EA + ((size_t)b * CS) * DV + d;
    u16* rp = RDIE + ((size_t)b * CS) * 384 + d;

    // preload step 0 into A set
    float4 wA0 = ld4(wp), wA1 = ld4(wp + 4), wA2 = ld4(wp + 8), wA3 = ld4(wp + 12);
    u32 eaA = *ep;
    float4 wB0, wB1, wB2, wB3;
    u32 eaB;

    int t = 0;
    for (; t + 2 <= CS; t += 2) {
        // prefetch step t+1 into B
        {
            const float* p = wp + WSTRIDE;
            wB0 = ld4(p); wB1 = ld4(p + 4); wB2 = ld4(p + 8); wB3 = ld4(p + 12);
            eaB = ep[DV];
        }
        scan_step(wA0, wA1, wA2, wA3, eaA, mg, rp, mv0, mv1, mv2, mv3);
        // prefetch step t+2 into A (uniform guard)
        if (t + 2 < CS) {
            const float* p = wp + 2 * WSTRIDE;
            wA0 = ld4(p); wA1 = ld4(p + 4); wA2 = ld4(p + 8); wA3 = ld4(p + 12);
            eaA = ep[2 * DV];
        }
        scan_step(wB0, wB1, wB2, wB3, eaB, mg, rp + 384, mv0, mv1, mv2, mv3);
        wp += 2 * WSTRIDE; ep += 2 * DV; rp += 2 * 384;
    }
    if (t < CS) {           // odd-CS tail (A set was prefetched in last pair)
        scan_step(wA0, wA1, wA2, wA3, eaA, mg, rp, mv0, mv1, mv2, mv3);
    }

    {
        float s[16] = {mv0.x, mv0.y, mv0.z, mv0.w, mv1.x, mv1.y, mv1.z, mv1.w,
                       mv2.x, mv2.y, mv2.z, mv2.w, mv3.x, mv3.y, mv3.z, mv3.w};
#pragma unroll
        for (int j = 0; j < 16; ++j) {
            int m = m0 + j;
            if (m < MM) MvSt[((size_t)b * MM + m) * DV + d] = s[j];
        }
    }
}

// ---------------------------------------------------------------------------
// loss + outputs
// ---------------------------------------------------------------------------
__global__ __launch_bounds__(256) void loss_part(
    const float* __restrict__ P, const int* __restrict__ target,
    const float* __restrict__ pred_b, float* __restrict__ out,
    float* __restrict__ R2, int s0, int CS, int Nc)
{
    int l = blockIdx.x * 256 + threadIdx.x;
    float le = 0.f, mf = 0.f;
    if (l < Nc) {
        int n = gmap(l, s0, CS);
        float p = P[l] + pred_b[0];
        int t = target[n];
        float y = (t >= 1) ? (float)(t - 1) : 0.f;
        float sig = 1.f / (1.f + __expf(-p));
        if (t >= 1) {
            mf = 1.f;
            le = fmaxf(p, 0.f) + log1pf(__expf(-fabsf(p))) - p * y;
        }
        out[1 + n] = sig * mf;
        out[1 + NROWS + n] = y * mf;
    }
#pragma unroll
    for (int off = 32; off; off >>= 1) {
        le += __shfl_down(le, off);
        mf += __shfl_down(mf, off);
    }
    __shared__ float sl[4], sm[4];
    int wid = threadIdx.x >> 6;
    if ((threadIdx.x & 63) == 0) { sl[wid] = le; sm[wid] = mf; }
    __syncthreads();
    if (threadIdx.x == 0) {
        atomicAdd(R2, sl[0] + sl[1] + sl[2] + sl[3]);
        atomicAdd(R2 + 1, sm[0] + sm[1] + sm[2] + sm[3]);
    }
}

__global__ void loss_fin(const float* __restrict__ R2, float* __restrict__ out)
{
    out[0] = R2[0] / fmaxf(R2[1], 1.f);
}

// ---------------------------------------------------------------------------
extern "C" void kernel_launch(void* const* d_in, const int* in_sizes, int n_in,
                              void* d_out, int out_size, void* d_ws, size_t ws_size,
                              hipStream_t stream)
{
    const int* q_data       = (const int*)d_in[0];
    const int* qa_data      = (const int*)d_in[1];
    const int* target       = (const int*)d_in[2];
    const int* time_data    = (const int*)d_in[3];
    const int* attempt_data = (const int*)d_in[4];
    const int* hint_data    = (const int*)d_in[5];
    const int* hintT_data   = (const int*)d_in[6];
    const float* q_emb    = (const float*)d_in[7];
    const float* qa_emb   = (const float*)d_in[8];
    const float* time_emb = (const float*)d_in[9];
    const float* att_emb  = (const float*)d_in[10];
    const float* ht_emb   = (const float*)d_in[11];
    const float* Mk       = (const float*)d_in[12];
    const float* Mv0      = (const float*)d_in[13];
    const float* diff_W   = (const float*)d_in[14];
    const float* diff_b   = (const float*)d_in[15];
    const float* diff2_W  = (const float*)d_in[16];
    const float* diff2_b  = (const float*)d_in[17];
    const float* erase_W  = (const float*)d_in[18];
    const float* erase_b  = (const float*)d_in[19];
    const float* add_W    = (const float*)d_in[20];
    const float* add_b    = (const float*)d_in[21];
    const float* read_W   = (const float*)d_in[22];
    const float* read_b   = (const float*)d_in[23];
    const float* pred_W   = (const float*)d_in[24];
    const float* pred_b   = (const float*)d_in[25];
    float* out = (float*)d_out;
    (void)in_sizes; (void)n_in; (void)out_size;

    // Adaptive chunking over S (any divisor of 500 works for scan v4).
    static const int cs_opts[] = {500, 250, 125, 100, 50, 25, 20, 10, 5, 4, 2};
    const size_t FIXED = 24100000ull;
    int CS = 0;
    for (int i = 0; i < 11; ++i) {
        size_t need = (size_t)NB * cs_opts[i] * 3080ull + FIXED;
        if (need <= ws_size) { CS = cs_opts[i]; break; }
    }
    if (CS == 0) return;
    const int NCH = SQ / CS;
    const int Nc = NB * CS;

    // Workspace layout (16B-aligned sections)
    float* MvSt  = (float*)d_ws;                         // [NB*MM*DV]
    float* wbuf  = MvSt + (size_t)NB * MM * DV;          // [Nc*64]
    float* bufP  = wbuf + (size_t)Nc * WSTRIDE;          // [Nc]
    float* bufR2 = bufP + Nc;                            // [4]
    u32*  EAu    = (u32*)(bufR2 + 4);                    // [Nc*256]
    u16*  Xp     = (u16*)(EAu + (size_t)Nc * 256);       // [2Nc*128]
    u16*  S3p    = Xp + (size_t)2 * Nc * 128;            // [Nc*128]
    u16*  QEp    = S3p + (size_t)Nc * 128;               // [Nc*128]
    u16*  RDIE   = QEp + (size_t)Nc * 128;               // [Nc*384]
    u16*  dWh    = RDIE + (size_t)Nc * 384;              // 16384
    u16*  d2Wh   = dWh + 16384;                          // 16384
    u16*  eWh    = d2Wh + 16384;                         // 65536
    u16*  aWh    = eWh + 65536;                          // 65536
    u16*  rWh    = aWh + 65536;                          // 196608
    u16*  qaEh   = rWh + 196608;                         // 5,120,256
    u16*  Mkh    = qaEh + 5120256;                       // 8,192 (64x128)

    // One-time weight/table conversions to fp16
    cvt16<<<16, 256, 0, stream>>>(diff_W,  dWh,  16384 / 4);
    cvt16<<<16, 256, 0, stream>>>(diff2_W, d2Wh, 16384 / 4);
    cvt16<<<64, 256, 0, stream>>>(erase_W, eWh,  65536 / 4);
    cvt16<<<64, 256, 0, stream>>>(add_W,   aWh,  65536 / 4);
    cvt16<<<192, 256, 0, stream>>>(read_W, rWh,  196608 / 4);
    cvt16<<<5001, 256, 0, stream>>>(qa_emb, qaEh, 5120256 / 4);
    mkcvt<<<8, 256, 0, stream>>>(Mk, Mkh);
    hipMemsetAsync(bufR2, 0, 4 * sizeof(float), stream);

    for (int c = 0; c < NCH; ++c) {
        const int s0 = c * CS;

        prep128<<<Nc / 8, 256, 0, stream>>>(
            q_data, time_data, attempt_data, hint_data, hintT_data,
            q_emb, time_emb, att_emb, ht_emb, Xp, S3p, QEp, s0, CS, Nc);

        // G1: [T1;T2] = tanh(lin1([X1;X2]))  (in-place Xp, 2Nc rows)
        gemm16<1><<<dim3(2 * Nc / 128, 1), 256, 0, stream>>>(
            Xp, dWh, nullptr, diff_b, nullptr, Xp, nullptr,
            nullptr, nullptr, nullptr, nullptr, nullptr, nullptr, 128, Nc, s0, CS);
        // G2: sig(lin2): rows<Nc -> tf; rows>=Nc -> x3 = qe + df*s3  (in-place)
        gemm16<2><<<dim3(2 * Nc / 128, 1), 256, 0, stream>>>(
            Xp, d2Wh, nullptr, diff2_b, nullptr, Xp, nullptr,
            QEp, S3p, nullptr, nullptr, nullptr, nullptr, 128, Nc, s0, CS);
        // G3: qp = lin1(x3) -> Xp[0:Nc); fused ie = qp + tf*te -> RDIE[:,256:)
        gemm16<3><<<dim3(Nc / 128, 1), 256, 0, stream>>>(
            Xp + (size_t)Nc * 128, dWh, nullptr, diff_b, nullptr, Xp, nullptr,
            nullptr, nullptr, time_data, time_emb, RDIE, nullptr, 128, Nc, s0, CS);
        // w = softmax(qp @ Mk^T) via MFMA
        wsoftmax_mfma<<<Nc / 128, 256, 0, stream>>>(Xp, Mkh, wbuf);
        // G4: e/a gates, gather-A from fp16 qa_emb, packed (e,a) -> EAu
        gemm16<4><<<dim3(Nc / 128, 4), 256, 0, stream>>>(
            qaEh, eWh, aWh, erase_b, add_b, nullptr, nullptr,
            nullptr, nullptr, qa_data, nullptr, (u16*)EAu, nullptr, 256, Nc, s0, CS);
        // scan v4 -> RD fp16 into RDIE[:,0:256)
        scan_kernel<<<NB, 1024, 0, stream>>>(wbuf, EAu, Mv0, MvSt, RDIE, CS, c == 0 ? 1 : 0);

        hipMemsetAsync(bufP, 0, (size_t)Nc * sizeof(float), stream);
        // G5: rc = tanh([rd|ie] @ read_W^T + b); pred partials -> bufP
        gemm16<5><<<dim3(Nc / 128, 4), 256, 0, stream>>>(
            RDIE, rWh, nullptr, read_b, nullptr, nullptr, bufP,
            nullptr, nullptr, nullptr, nullptr, nullptr, pred_W, 384, Nc, s0, CS);

        loss_part<<<Nc / 256, 256, 0, stream>>>(bufP, target, pred_b, out, bufR2, s0, CS, Nc);
    }

    loss_fin<<<1, 1, 0, stream>>>(bufR2, out);
}

// Round 10
// 904.108 us; speedup vs baseline: 1.1014x; 1.1014x over previous
//
#include <hip/hip_runtime.h>
#include <cstdint>
#include <cstddef>

// Problem constants
#define NB 256
#define SQ 500
#define NROWS (NB * SQ)   // 128000
#define DQ 128
#define DV 256
#define MM 50
#define FF 512
#define WSTRIDE 64        // padded w-row stride (cols 50..63 zero)
#define STILE 10          // scan steps per LDS tile

typedef _Float16 half8 __attribute__((ext_vector_type(8)));
typedef float floatx4 __attribute__((ext_vector_type(4)));
typedef unsigned short u16;
typedef unsigned int u32;

__device__ __forceinline__ float4 ld4(const float* p) {
    return *reinterpret_cast<const float4*>(p);
}
__device__ __forceinline__ float sigf(float x) { return 1.f / (1.f + __expf(-x)); }
__device__ __forceinline__ float tanhfast(float x) { return 2.f / (1.f + __expf(-2.f * x)) - 1.f; }
__device__ __forceinline__ int gmap(int l, int s0, int CS) {
    int b = (unsigned)l / (unsigned)CS;
    return b * SQ + s0 + (l - b * CS);
}
__device__ __forceinline__ void st4h(u16* dst, float4 v) {
    _Float16 h0 = (_Float16)v.x, h1 = (_Float16)v.y, h2 = (_Float16)v.z, h3 = (_Float16)v.w;
    ushort4 u;
    u.x = *(u16*)&h0; u.y = *(u16*)&h1; u.z = *(u16*)&h2; u.w = *(u16*)&h3;
    *(ushort4*)dst = u;
}
__device__ __forceinline__ float h2f(u16 b) { _Float16 h; *(u16*)&h = b; return (float)h; }
__device__ __forceinline__ u16 f2h(float x) { _Float16 h = (_Float16)x; return *(u16*)&h; }

// ---------------------------------------------------------------------------
// fp32 -> fp16 conversion (vec4)
// ---------------------------------------------------------------------------
__global__ __launch_bounds__(256) void cvt16(
    const float* __restrict__ s, u16* __restrict__ d, int n4)
{
    int i = blockIdx.x * 256 + threadIdx.x;
    if (i < n4) st4h(d + 4 * (size_t)i, ld4(s + 4 * (size_t)i));
}

// ---------------------------------------------------------------------------
// Mk [50,128] fp32 -> Mkh [64,128] fp16, rows 50..63 zeroed
// ---------------------------------------------------------------------------
__global__ __launch_bounds__(256) void mkcvt(
    const float* __restrict__ Mk, u16* __restrict__ Mkh)
{
    int i = blockIdx.x * 256 + threadIdx.x;   // 2048 float4 slots
    if (i >= 64 * 32) return;
    int row = i >> 5;
    float4 v = (row < MM) ? ld4(Mk + (size_t)row * DQ + (i & 31) * 4)
                          : float4{0.f, 0.f, 0.f, 0.f};
    st4h(Mkh + 4 * (size_t)i, v);
}

// ---------------------------------------------------------------------------
// prep: Xp rows [0,Nc) = fp16(te+qe); rows [Nc,2Nc) = fp16(he+hte+ae+qe);
//       S3p = fp16(he+hte+ae); QEp = fp16(qe)
// ---------------------------------------------------------------------------
__global__ __launch_bounds__(256) void prep128(
    const int* __restrict__ q_data, const int* __restrict__ time_data,
    const int* __restrict__ attempt_data, const int* __restrict__ hint_data,
    const int* __restrict__ hintT_data,
    const float* __restrict__ q_emb, const float* __restrict__ time_emb,
    const float* __restrict__ attempt_emb, const float* __restrict__ ht_emb,
    u16* __restrict__ Xp, u16* __restrict__ S3p, u16* __restrict__ QEp,
    int s0, int CS, int Nc)
{
    int g = blockIdx.x * 256 + threadIdx.x;
    int l = g >> 5;
    int kq = (g & 31) << 2;
    if (l >= Nc) return;
    int n = gmap(l, s0, CS);
    float4 qe  = ld4(q_emb       + (size_t)q_data[n]       * DQ + kq);
    float4 te  = ld4(time_emb    + (size_t)time_data[n]    * DQ + kq);
    float4 ae  = ld4(attempt_emb + (size_t)attempt_data[n] * DQ + kq);
    float4 he  = ld4(ht_emb      + (size_t)hint_data[n]    * DQ + kq);
    float4 hte = ld4(ht_emb      + (size_t)hintT_data[n]   * DQ + kq);
    size_t off = (size_t)l * DQ + kq;
    float4 x1, s3, x2;
    x1.x = te.x + qe.x; x1.y = te.y + qe.y; x1.z = te.z + qe.z; x1.w = te.w + qe.w;
    s3.x = he.x + hte.x + ae.x; s3.y = he.y + hte.y + ae.y;
    s3.z = he.z + hte.z + ae.z; s3.w = he.w + hte.w + ae.w;
    x2.x = s3.x + qe.x; x2.y = s3.y + qe.y; x2.z = s3.z + qe.z; x2.w = s3.w + qe.w;
    st4h(Xp + off, x1);
    st4h(Xp + (size_t)Nc * DQ + off, x2);
    st4h(S3p + off, s3);
    st4h(QEp + off, qe);
}

// ---------------------------------------------------------------------------
// fp16 MFMA GEMM: Y = epi(act(A @ W^T + bias)), BM=BN=128, BK=32, 4 waves,
// wave tile 64x64 = 4x4 of v_mfma_f32_16x16x32_f16.
// MODE 1: tanh -> fp16 Yh (stride 128)               [lin1 on 2Nc rows]
// MODE 2: sig; row<Nc: tf->Yh; row>=Nc: x3=qe+v*s3 -> Yh  [lin2 batched]
// MODE 3: none; qp->Yh; fused ie=qp+tf*te -> AUX[,256:384] [lin1(X3)+ew_ie]
// MODE 4: gather A=qaE[idx]; by<2: sig->e, else tanh->a; packed u16 pairs->AUX
// MODE 5: tanh(rc); pred-partial reduce -> atomicAdd Yf    [readout+pred]
// ---------------------------------------------------------------------------
template <int MODE>
__global__ __launch_bounds__(256, 3) void gemm16(
    const u16* __restrict__ A, const u16* __restrict__ W0,
    const u16* __restrict__ W1, const float* __restrict__ b0,
    const float* __restrict__ b1, u16* __restrict__ Yh,
    float* __restrict__ Yf,
    const u16* __restrict__ QEp, const u16* __restrict__ S3p,
    const int* __restrict__ idx, const float* __restrict__ gtab,
    u16* __restrict__ AUX, const float* __restrict__ predW,
    int K, int Nc, int s0, int CS)
{
    __shared__ u16 smem[2 * 128 * 40];   // 20480 B: A-tile | B-tile (pitch 80B)
    u16* At = smem;
    u16* Bt = smem + 128 * 40;
    const int tid = threadIdx.x;
    const int row0 = blockIdx.x * 128;
    const int by = blockIdx.y;

    const u16* Wp;
    int col0;
    if constexpr (MODE == 4) { Wp = (by < 2) ? W0 : W1; col0 = (by & 1) * 128; }
    else { Wp = W0; col0 = by * 128; }
    const float* bias = (MODE == 4 && by >= 2) ? b1 : b0;

    floatx4 acc[4][4];
#pragma unroll
    for (int m = 0; m < 4; ++m)
#pragma unroll
        for (int n = 0; n < 4; ++n) acc[m][n] = (floatx4)0.f;

    const int lane = tid & 63, wv = tid >> 6;
    const int wr = (wv >> 1) * 64, wc = (wv & 1) * 64;
    const int q = lane >> 4, c0 = lane & 15;

    for (int kt = 0; kt < K; kt += 32) {
#pragma unroll
        for (int i = 0; i < 4; ++i) {
            int c = tid + i * 256;          // [0,1024)
            if (c < 512) {
                int r = c >> 2, seg = c & 3;
                const u16* src;
                if constexpr (MODE == 4) {
                    int g = idx[gmap(row0 + r, s0, CS)];
                    src = A + (size_t)g * K + kt + seg * 8;
                } else {
                    src = A + (size_t)(row0 + r) * K + kt + seg * 8;
                }
                *(uint4*)&At[r * 40 + seg * 8] = *(const uint4*)src;
            } else {
                int cb = c - 512;
                int r = cb >> 2, seg = cb & 3;
                const u16* src = Wp + (size_t)(col0 + r) * K + kt + seg * 8;
                *(uint4*)&Bt[r * 40 + seg * 8] = *(const uint4*)src;
            }
        }
        __syncthreads();
        half8 af[4], bf[4];
#pragma unroll
        for (int m = 0; m < 4; ++m) af[m] = *(half8*)&At[(wr + m * 16 + c0) * 40 + q * 8];
#pragma unroll
        for (int n = 0; n < 4; ++n) bf[n] = *(half8*)&Bt[(wc + n * 16 + c0) * 40 + q * 8];
#pragma unroll
        for (int m = 0; m < 4; ++m)
#pragma unroll
            for (int n = 0; n < 4; ++n)
                acc[m][n] = __builtin_amdgcn_mfma_f32_16x16x32_f16(af[m], bf[n], acc[m][n], 0, 0, 0);
        __syncthreads();
    }

    float bv[4];
#pragma unroll
    for (int n = 0; n < 4; ++n) bv[n] = bias[col0 + wc + n * 16 + c0];

    if constexpr (MODE == 5) {
        float pw[4];
#pragma unroll
        for (int n = 0; n < 4; ++n) pw[n] = predW[col0 + wc + n * 16 + c0];
        float* red = (float*)smem;          // [128][33] = 16896 B <= 20480
#pragma unroll
        for (int m = 0; m < 4; ++m)
#pragma unroll
            for (int r4 = 0; r4 < 4; ++r4) {
                int row = wr + m * 16 + q * 4 + r4;
                float pp = 0.f;
#pragma unroll
                for (int n = 0; n < 4; ++n)
                    pp = fmaf(tanhfast(acc[m][n][r4] + bv[n]), pw[n], pp);
                red[row * 33 + (wv & 1) * 16 + c0] = pp;
            }
        __syncthreads();
        if (tid < 128) {
            float s = 0.f;
#pragma unroll
            for (int j = 0; j < 32; ++j) s += red[tid * 33 + j];
            atomicAdd(&Yf[row0 + tid], s);
        }
    } else {
#pragma unroll
        for (int m = 0; m < 4; ++m)
#pragma unroll
            for (int r4 = 0; r4 < 4; ++r4) {
                int row = row0 + wr + m * 16 + q * 4 + r4;
#pragma unroll
                for (int n = 0; n < 4; ++n) {
                    int col = col0 + wc + n * 16 + c0;
                    float v = acc[m][n][r4] + bv[n];
                    if constexpr (MODE == 1) {
                        Yh[(size_t)row * 128 + col] = f2h(tanhfast(v));
                    } else if constexpr (MODE == 2) {
                        v = sigf(v);
                        if (row < Nc) {
                            Yh[(size_t)row * 128 + col] = f2h(v);
                        } else {
                            size_t o = (size_t)(row - Nc) * 128 + col;
                            float qe = h2f(QEp[o]), s3 = h2f(S3p[o]);
                            Yh[(size_t)row * 128 + col] = f2h(fmaf(v, s3, qe));
                        }
                    } else if constexpr (MODE == 3) {
                        size_t o = (size_t)row * 128 + col;
                        float tf = h2f(Yh[o]);   // read tf BEFORE overwriting with qp
                        float te = gtab[(size_t)idx[gmap(row, s0, CS)] * 128 + col];
                        AUX[(size_t)row * 384 + 256 + col] = f2h(fmaf(tf, te, v));
                        Yh[o] = f2h(v);
                    } else { // MODE 4
                        bool isE = (by < 2);
                        v = isE ? sigf(v) : tanhfast(v);
                        AUX[((size_t)row * 256 + col) * 2 + (isE ? 0 : 1)] = f2h(v);
                    }
                }
            }
    }
}

// ---------------------------------------------------------------------------
// w = softmax(qp @ Mk^T) via MFMA. Block: 128 rows x 64 cols (50 live).
// Logits -> LDS (pitch 67), row softmax, zero cols 50..63, coalesced store
// to Wb (stride WSTRIDE=64).
// ---------------------------------------------------------------------------
__global__ __launch_bounds__(256) void wsoftmax_mfma(
    const u16* __restrict__ QP, const u16* __restrict__ Mkh,
    float* __restrict__ Wb)
{
    __shared__ float Sred[128 * 67];        // 34304 B; head doubles as At/Bt
    u16* At = (u16*)Sred;                   // [128][40] fp16 = 10240 B
    u16* Bt = At + 128 * 40;                // [64][40]  fp16 =  5120 B
    const int tid = threadIdx.x;
    const int row0 = blockIdx.x * 128;
    const int lane = tid & 63, wv = tid >> 6;
    const int wr = wv * 32;                 // wave: 32 rows x 64 cols
    const int q = lane >> 4, c0 = lane & 15;

    floatx4 acc[2][4];
#pragma unroll
    for (int m = 0; m < 2; ++m)
#pragma unroll
        for (int n = 0; n < 4; ++n) acc[m][n] = (floatx4)0.f;

    for (int kt = 0; kt < DQ; kt += 32) {
#pragma unroll
        for (int i = 0; i < 3; ++i) {
            int c = tid + i * 256;          // [0,768)
            if (c < 512) {
                int r = c >> 2, seg = c & 3;
                *(uint4*)&At[r * 40 + seg * 8] =
                    *(const uint4*)(QP + (size_t)(row0 + r) * DQ + kt + seg * 8);
            } else {
                int cb = c - 512;
                int r = cb >> 2, seg = cb & 3;
                *(uint4*)&Bt[r * 40 + seg * 8] =
                    *(const uint4*)(Mkh + (size_t)r * DQ + kt + seg * 8);
            }
        }
        __syncthreads();
        half8 af[2], bf[4];
#pragma unroll
        for (int m = 0; m < 2; ++m) af[m] = *(half8*)&At[(wr + m * 16 + c0) * 40 + q * 8];
#pragma unroll
        for (int n = 0; n < 4; ++n) bf[n] = *(half8*)&Bt[(n * 16 + c0) * 40 + q * 8];
#pragma unroll
        for (int m = 0; m < 2; ++m)
#pragma unroll
            for (int n = 0; n < 4; ++n)
                acc[m][n] = __builtin_amdgcn_mfma_f32_16x16x32_f16(af[m], bf[n], acc[m][n], 0, 0, 0);
        __syncthreads();
    }

    // dump logits to LDS: row = wr + m*16 + q*4 + r, col = n*16 + c0
#pragma unroll
    for (int m = 0; m < 2; ++m)
#pragma unroll
        for (int r4 = 0; r4 < 4; ++r4) {
            int row = wr + m * 16 + q * 4 + r4;
#pragma unroll
            for (int n = 0; n < 4; ++n)
                Sred[row * 67 + n * 16 + c0] = acc[m][n][r4];
        }
    __syncthreads();

    // row-wise softmax over 50 live cols; zero pad cols 50..63
    if (tid < 128) {
        float* s = &Sred[tid * 67];
        float mx = -3.0e38f;
#pragma unroll
        for (int m = 0; m < MM; ++m) mx = fmaxf(mx, s[m]);
        float sum = 0.f;
#pragma unroll
        for (int m = 0; m < MM; ++m) { float e = __expf(s[m] - mx); s[m] = e; sum += e; }
        float inv = 1.f / sum;
#pragma unroll
        for (int m = 0; m < MM; ++m) s[m] *= inv;
#pragma unroll
        for (int m = MM; m < 64; ++m) s[m] = 0.f;
    }
    __syncthreads();

    // coalesced store: 128 rows x 16 float4
    for (int i = tid; i < 128 * 16; i += 256) {
        int row = i >> 4, seg = i & 15;
        float4 v;
        v.x = Sred[row * 67 + seg * 4 + 0];
        v.y = Sred[row * 67 + seg * 4 + 1];
        v.z = Sred[row * 67 + seg * 4 + 2];
        v.w = Sred[row * 67 + seg * 4 + 3];
        *(float4*)(Wb + (size_t)(row0 + row) * WSTRIDE + seg * 4) = v;
    }
}

// ---------------------------------------------------------------------------
// DKVMN scan v5: 512 blocks (batch x d-half) x 1024 threads (16 waves =
// 8 waves/SIMD at 2 blocks/CU). m-split 8-way: wave = 8 d x 8 mg; mv[8] in
// two named float4s. w + e/a staged in double-buffered LDS tiles of STILE
// steps (broadcast ds_reads, one barrier per tile) -- the hot loop has NO
// global loads, so conservative vmcnt(0) cannot expose memory latency.
// ---------------------------------------------------------------------------
__device__ __forceinline__ float dot8(
    const float4& w0, const float4& w1, const float4& m0, const float4& m1)
{
    float r = w0.x * m0.x;
    r = fmaf(w0.y, m0.y, r); r = fmaf(w0.z, m0.z, r); r = fmaf(w0.w, m0.w, r);
    r = fmaf(w1.x, m1.x, r); r = fmaf(w1.y, m1.y, r); r = fmaf(w1.z, m1.z, r); r = fmaf(w1.w, m1.w, r);
    return r;
}

__device__ __forceinline__ void upd4(float4& mv, const float4& wv, float e, float a)
{
    mv.x = fmaf(mv.x, fmaf(-wv.x, e, 1.f), wv.x * a);
    mv.y = fmaf(mv.y, fmaf(-wv.y, e, 1.f), wv.y * a);
    mv.z = fmaf(mv.z, fmaf(-wv.z, e, 1.f), wv.z * a);
    mv.w = fmaf(mv.w, fmaf(-wv.w, e, 1.f), wv.w * a);
}

__global__ __launch_bounds__(1024, 8) void scan_kernel(
    const float* __restrict__ Wb, const u32* __restrict__ EA,
    const float* __restrict__ Mv0, float* __restrict__ MvSt,
    u16* __restrict__ RDIE, int CS, int first)
{
    __shared__ float wt[2][STILE * 64];    // 2 x 2560 B
    __shared__ u32  eat[2][STILE * 128];   // 2 x 5120 B
    const int bb = blockIdx.x >> 1;
    const int dh = blockIdx.x & 1;
    const int tid = threadIdx.x;
    const int lane = tid & 63;
    const int wave = tid >> 6;
    const int mg = lane >> 3;          // 0..7
    const int dl = lane & 7;
    const int dloc = wave * 8 + dl;    // 0..127
    const int d = dh * 128 + dloc;     // 0..255
    const int m0 = mg * 8;

    float4 mv0, mv1;
    {
        float t0[8];
#pragma unroll
        for (int j = 0; j < 8; ++j) {
            int m = m0 + j;
            t0[j] = (m < MM) ? (first ? Mv0[m * DV + d]
                                      : MvSt[((size_t)bb * MM + m) * DV + d]) : 0.f;
        }
        mv0 = float4{t0[0], t0[1], t0[2], t0[3]};
        mv1 = float4{t0[4], t0[5], t0[6], t0[7]};
    }

    const float* wbase = Wb + (size_t)bb * CS * WSTRIDE;
    const u32* ebase = EA + (size_t)bb * CS * DV + dh * 128;
    u16* rp = RDIE + (size_t)bb * CS * 384 + d;

    const int NT = (CS + STILE - 1) / STILE;
    const bool wload = (tid < STILE * 16);                 // 160 float4 loaders
    const bool eload = (tid >= 256 && tid < 256 + STILE * 32);  // 320 uint4 loaders
    const int wj = tid;                // 0..159  -> float4 index
    const int ej = tid - 256;          // 0..319  -> uint4 index
    const int es = eload ? (ej >> 5) : 0;       // step within tile
    const int ec = eload ? (ej & 31) : 0;       // uint4 within 128-d row

    // Preload tile 0
    if (wload) *(float4*)&wt[0][wj * 4] = ld4(wbase + wj * 4);
    if (eload) *(uint4*)&eat[0][es * 128 + ec * 4] =
        *(const uint4*)(ebase + (size_t)es * DV + ec * 4);
    __syncthreads();

    int cur = 0;
    for (int tile = 0; tile < NT; ++tile) {
        const int base = tile * STILE;
        const int nst = (CS - base < STILE) ? (CS - base) : STILE;
        const bool have = (tile + 1 < NT);

        // Prefetch next tile into regs (overlaps the compute below; buffers
        // are padded by STILE rows so the tail read is in-bounds)
        float4 wv{0.f, 0.f, 0.f, 0.f};
        uint4 ev{0, 0, 0, 0};
        if (have) {
            if (wload) wv = ld4(wbase + (size_t)(base + STILE) * WSTRIDE + wj * 4);
            if (eload) ev = *(const uint4*)(ebase + (size_t)(base + STILE + es) * DV + ec * 4);
        }

        for (int s = 0; s < nst; ++s) {
            float4 w0 = *(const float4*)&wt[cur][s * 64 + m0];
            float4 w1 = *(const float4*)&wt[cur][s * 64 + m0 + 4];
            u32 eav = eat[cur][s * 128 + dloc];
            const float e = h2f((u16)(eav & 0xffff));
            const float a = h2f((u16)(eav >> 16));
            float r = dot8(w0, w1, mv0, mv1);
            r += __shfl_xor(r, 8);
            r += __shfl_xor(r, 16);
            r += __shfl_xor(r, 32);
            if (mg == 0) rp[(size_t)(base + s) * 384] = f2h(r);
            upd4(mv0, w0, e, a);
            upd4(mv1, w1, e, a);
        }

        if (have) {
            if (wload) *(float4*)&wt[1 - cur][wj * 4] = wv;
            if (eload) *(uint4*)&eat[1 - cur][es * 128 + ec * 4] = ev;
            __syncthreads();
            cur ^= 1;
        }
    }

    {
        float s0 = mv0.x, s1 = mv0.y, s2 = mv0.z, s3 = mv0.w;
        float s4 = mv1.x, s5 = mv1.y, s6 = mv1.z, s7 = mv1.w;
        float sv[8] = {s0, s1, s2, s3, s4, s5, s6, s7};
#pragma unroll
        for (int j = 0; j < 8; ++j) {
            int m = m0 + j;
            if (m < MM) MvSt[((size_t)bb * MM + m) * DV + d] = sv[j];
        }
    }
}

// ---------------------------------------------------------------------------
// loss + outputs
// ---------------------------------------------------------------------------
__global__ __launch_bounds__(256) void loss_part(
    const float* __restrict__ P, const int* __restrict__ target,
    const float* __restrict__ pred_b, float* __restrict__ out,
    float* __restrict__ R2, int s0, int CS, int Nc)
{
    int l = blockIdx.x * 256 + threadIdx.x;
    float le = 0.f, mf = 0.f;
    if (l < Nc) {
        int n = gmap(l, s0, CS);
        float p = P[l] + pred_b[0];
        int t = target[n];
        float y = (t >= 1) ? (float)(t - 1) : 0.f;
        float sig = 1.f / (1.f + __expf(-p));
        if (t >= 1) {
            mf = 1.f;
            le = fmaxf(p, 0.f) + log1pf(__expf(-fabsf(p))) - p * y;
        }
        out[1 + n] = sig * mf;
        out[1 + NROWS + n] = y * mf;
    }
#pragma unroll
    for (int off = 32; off; off >>= 1) {
        le += __shfl_down(le, off);
        mf += __shfl_down(mf, off);
    }
    __shared__ float sl[4], sm[4];
    int wid = threadIdx.x >> 6;
    if ((threadIdx.x & 63) == 0) { sl[wid] = le; sm[wid] = mf; }
    __syncthreads();
    if (threadIdx.x == 0) {
        atomicAdd(R2, sl[0] + sl[1] + sl[2] + sl[3]);
        atomicAdd(R2 + 1, sm[0] + sm[1] + sm[2] + sm[3]);
    }
}

__global__ void loss_fin(const float* __restrict__ R2, float* __restrict__ out)
{
    out[0] = R2[0] / fmaxf(R2[1], 1.f);
}

// ---------------------------------------------------------------------------
extern "C" void kernel_launch(void* const* d_in, const int* in_sizes, int n_in,
                              void* d_out, int out_size, void* d_ws, size_t ws_size,
                              hipStream_t stream)
{
    const int* q_data       = (const int*)d_in[0];
    const int* qa_data      = (const int*)d_in[1];
    const int* target       = (const int*)d_in[2];
    const int* time_data    = (const int*)d_in[3];
    const int* attempt_data = (const int*)d_in[4];
    const int* hint_data    = (const int*)d_in[5];
    const int* hintT_data   = (const int*)d_in[6];
    const float* q_emb    = (const float*)d_in[7];
    const float* qa_emb   = (const float*)d_in[8];
    const float* time_emb = (const float*)d_in[9];
    const float* att_emb  = (const float*)d_in[10];
    const float* ht_emb   = (const float*)d_in[11];
    const float* Mk       = (const float*)d_in[12];
    const float* Mv0      = (const float*)d_in[13];
    const float* diff_W   = (const float*)d_in[14];
    const float* diff_b   = (const float*)d_in[15];
    const float* diff2_W  = (const float*)d_in[16];
    const float* diff2_b  = (const float*)d_in[17];
    const float* erase_W  = (const float*)d_in[18];
    const float* erase_b  = (const float*)d_in[19];
    const float* add_W    = (const float*)d_in[20];
    const float* add_b    = (const float*)d_in[21];
    const float* read_W   = (const float*)d_in[22];
    const float* read_b   = (const float*)d_in[23];
    const float* pred_W   = (const float*)d_in[24];
    const float* pred_b   = (const float*)d_in[25];
    float* out = (float*)d_out;
    (void)in_sizes; (void)n_in; (void)out_size;

    // Adaptive chunking over S. Per-row 3080 B; FIXED ~24.1 MB (incl. STILE
    // padding for wbuf/EAu tail prefetch).
    static const int cs_opts[] = {500, 250, 125, 100, 50, 25, 20, 10, 5, 4, 2};
    const size_t FIXED = 24200000ull;
    int CS = 0;
    for (int i = 0; i < 11; ++i) {
        size_t need = (size_t)NB * cs_opts[i] * 3080ull + FIXED;
        if (need <= ws_size) { CS = cs_opts[i]; break; }
    }
    if (CS == 0) return;
    const int NCH = SQ / CS;
    const int Nc = NB * CS;

    // Workspace layout (16B-aligned sections; wbuf/EAu padded by STILE rows)
    float* MvSt  = (float*)d_ws;                         // [NB*MM*DV]
    float* wbuf  = MvSt + (size_t)NB * MM * DV;          // [Nc*64 + pad]
    float* bufP  = wbuf + (size_t)Nc * WSTRIDE + STILE * WSTRIDE;   // [Nc]
    float* bufR2 = bufP + Nc;                            // [4]
    u32*  EAu    = (u32*)(bufR2 + 4);                    // [Nc*256 + pad]
    u16*  Xp     = (u16*)(EAu + (size_t)Nc * 256 + STILE * 256);    // [2Nc*128]
    u16*  S3p    = Xp + (size_t)2 * Nc * 128;            // [Nc*128]
    u16*  QEp    = S3p + (size_t)Nc * 128;               // [Nc*128]
    u16*  RDIE   = QEp + (size_t)Nc * 128;               // [Nc*384]
    u16*  dWh    = RDIE + (size_t)Nc * 384;              // 16384
    u16*  d2Wh   = dWh + 16384;                          // 16384
    u16*  eWh    = d2Wh + 16384;                         // 65536
    u16*  aWh    = eWh + 65536;                          // 65536
    u16*  rWh    = aWh + 65536;                          // 196608
    u16*  qaEh   = rWh + 196608;                         // 5,120,256
    u16*  Mkh    = qaEh + 5120256;                       // 8,192 (64x128)

    // One-time weight/table conversions to fp16
    cvt16<<<16, 256, 0, stream>>>(diff_W,  dWh,  16384 / 4);
    cvt16<<<16, 256, 0, stream>>>(diff2_W, d2Wh, 16384 / 4);
    cvt16<<<64, 256, 0, stream>>>(erase_W, eWh,  65536 / 4);
    cvt16<<<64, 256, 0, stream>>>(add_W,   aWh,  65536 / 4);
    cvt16<<<192, 256, 0, stream>>>(read_W, rWh,  196608 / 4);
    cvt16<<<5001, 256, 0, stream>>>(qa_emb, qaEh, 5120256 / 4);
    mkcvt<<<8, 256, 0, stream>>>(Mk, Mkh);
    hipMemsetAsync(bufR2, 0, 4 * sizeof(float), stream);

    for (int c = 0; c < NCH; ++c) {
        const int s0 = c * CS;

        prep128<<<Nc / 8, 256, 0, stream>>>(
            q_data, time_data, attempt_data, hint_data, hintT_data,
            q_emb, time_emb, att_emb, ht_emb, Xp, S3p, QEp, s0, CS, Nc);

        // G1: [T1;T2] = tanh(lin1([X1;X2]))  (in-place Xp, 2Nc rows)
        gemm16<1><<<dim3(2 * Nc / 128, 1), 256, 0, stream>>>(
            Xp, dWh, nullptr, diff_b, nullptr, Xp, nullptr,
            nullptr, nullptr, nullptr, nullptr, nullptr, nullptr, 128, Nc, s0, CS);
        // G2: sig(lin2): rows<Nc -> tf; rows>=Nc -> x3 = qe + df*s3  (in-place)
        gemm16<2><<<dim3(2 * Nc / 128, 1), 256, 0, stream>>>(
            Xp, d2Wh, nullptr, diff2_b, nullptr, Xp, nullptr,
            QEp, S3p, nullptr, nullptr, nullptr, nullptr, 128, Nc, s0, CS);
        // G3: qp = lin1(x3) -> Xp[0:Nc); fused ie = qp + tf*te -> RDIE[:,256:)
        gemm16<3><<<dim3(Nc / 128, 1), 256, 0, stream>>>(
            Xp + (size_t)Nc * 128, dWh, nullptr, diff_b, nullptr, Xp, nullptr,
            nullptr, nullptr, time_data, time_emb, RDIE, nullptr, 128, Nc, s0, CS);
        // w = softmax(qp @ Mk^T) via MFMA
        wsoftmax_mfma<<<Nc / 128, 256, 0, stream>>>(Xp, Mkh, wbuf);
        // G4: e/a gates, gather-A from fp16 qa_emb, packed (e,a) -> EAu
        gemm16<4><<<dim3(Nc / 128, 4), 256, 0, stream>>>(
            qaEh, eWh, aWh, erase_b, add_b, nullptr, nullptr,
            nullptr, nullptr, qa_data, nullptr, (u16*)EAu, nullptr, 256, Nc, s0, CS);
        // scan v5 -> RD fp16 into RDIE[:,0:256)
        scan_kernel<<<NB * 2, 1024, 0, stream>>>(wbuf, EAu, Mv0, MvSt, RDIE, CS, c == 0 ? 1 : 0);

        hipMemsetAsync(bufP, 0, (size_t)Nc * sizeof(float), stream);
        // G5: rc = tanh([rd|ie] @ read_W^T + b); pred partials -> bufP
        gemm16<5><<<dim3(Nc / 128, 4), 256, 0, stream>>>(
            RDIE, rWh, nullptr, read_b, nullptr, nullptr, bufP,
            nullptr, nullptr, nullptr, nullptr, nullptr, pred_W, 384, Nc, s0, CS);

        loss_part<<<Nc / 256, 256, 0, stream>>>(bufP, target, pred_b, out, bufR2, s0, CS, Nc);
    }

    loss_fin<<<1, 1, 0, stream>>>(bufR2, out);
}

// Round 11
// 874.460 us; speedup vs baseline: 1.1387x; 1.0339x over previous
//
#include <hip/hip_runtime.h>
#include <cstdint>
#include <cstddef>

// Problem constants
#define NB 256
#define SQ 500
#define NROWS (NB * SQ)   // 128000
#define DQ 128
#define DV 256
#define MM 50
#define FF 512
#define WSTRIDE 64        // padded w-row stride (cols 50..63 zero)
#define STILE 10          // scan steps per LDS tile

typedef _Float16 half8 __attribute__((ext_vector_type(8)));
typedef float floatx4 __attribute__((ext_vector_type(4)));
typedef unsigned short u16;
typedef unsigned int u32;

__device__ __forceinline__ float4 ld4(const float* p) {
    return *reinterpret_cast<const float4*>(p);
}
__device__ __forceinline__ float sigf(float x) { return 1.f / (1.f + __expf(-x)); }
__device__ __forceinline__ float tanhfast(float x) { return 2.f / (1.f + __expf(-2.f * x)) - 1.f; }
__device__ __forceinline__ int gmap(int l, int s0, int CS) {
    int b = (unsigned)l / (unsigned)CS;
    return b * SQ + s0 + (l - b * CS);
}
__device__ __forceinline__ void st4h(u16* dst, float4 v) {
    _Float16 h0 = (_Float16)v.x, h1 = (_Float16)v.y, h2 = (_Float16)v.z, h3 = (_Float16)v.w;
    ushort4 u;
    u.x = *(u16*)&h0; u.y = *(u16*)&h1; u.z = *(u16*)&h2; u.w = *(u16*)&h3;
    *(ushort4*)dst = u;
}
__device__ __forceinline__ float h2f(u16 b) { _Float16 h; *(u16*)&h = b; return (float)h; }
__device__ __forceinline__ u16 f2h(float x) { _Float16 h = (_Float16)x; return *(u16*)&h; }

// ---------------------------------------------------------------------------
// fp32 -> fp16 conversion (vec4)
// ---------------------------------------------------------------------------
__global__ __launch_bounds__(256) void cvt16(
    const float* __restrict__ s, u16* __restrict__ d, int n4)
{
    int i = blockIdx.x * 256 + threadIdx.x;
    if (i < n4) st4h(d + 4 * (size_t)i, ld4(s + 4 * (size_t)i));
}

// ---------------------------------------------------------------------------
// Mk [50,128] fp32 -> Mkh [64,128] fp16, rows 50..63 zeroed
// ---------------------------------------------------------------------------
__global__ __launch_bounds__(256) void mkcvt(
    const float* __restrict__ Mk, u16* __restrict__ Mkh)
{
    int i = blockIdx.x * 256 + threadIdx.x;   // 2048 float4 slots
    if (i >= 64 * 32) return;
    int row = i >> 5;
    float4 v = (row < MM) ? ld4(Mk + (size_t)row * DQ + (i & 31) * 4)
                          : float4{0.f, 0.f, 0.f, 0.f};
    st4h(Mkh + 4 * (size_t)i, v);
}

// ---------------------------------------------------------------------------
// prep: Xp rows [0,Nc) = fp16(te+qe); rows [Nc,2Nc) = fp16(he+hte+ae+qe);
//       S3p = fp16(he+hte+ae); QEp = fp16(qe)
// ---------------------------------------------------------------------------
__global__ __launch_bounds__(256) void prep128(
    const int* __restrict__ q_data, const int* __restrict__ time_data,
    const int* __restrict__ attempt_data, const int* __restrict__ hint_data,
    const int* __restrict__ hintT_data,
    const float* __restrict__ q_emb, const float* __restrict__ time_emb,
    const float* __restrict__ attempt_emb, const float* __restrict__ ht_emb,
    u16* __restrict__ Xp, u16* __restrict__ S3p, u16* __restrict__ QEp,
    int s0, int CS, int Nc)
{
    int g = blockIdx.x * 256 + threadIdx.x;
    int l = g >> 5;
    int kq = (g & 31) << 2;
    if (l >= Nc) return;
    int n = gmap(l, s0, CS);
    float4 qe  = ld4(q_emb       + (size_t)q_data[n]       * DQ + kq);
    float4 te  = ld4(time_emb    + (size_t)time_data[n]    * DQ + kq);
    float4 ae  = ld4(attempt_emb + (size_t)attempt_data[n] * DQ + kq);
    float4 he  = ld4(ht_emb      + (size_t)hint_data[n]    * DQ + kq);
    float4 hte = ld4(ht_emb      + (size_t)hintT_data[n]   * DQ + kq);
    size_t off = (size_t)l * DQ + kq;
    float4 x1, s3, x2;
    x1.x = te.x + qe.x; x1.y = te.y + qe.y; x1.z = te.z + qe.z; x1.w = te.w + qe.w;
    s3.x = he.x + hte.x + ae.x; s3.y = he.y + hte.y + ae.y;
    s3.z = he.z + hte.z + ae.z; s3.w = he.w + hte.w + ae.w;
    x2.x = s3.x + qe.x; x2.y = s3.y + qe.y; x2.z = s3.z + qe.z; x2.w = s3.w + qe.w;
    st4h(Xp + off, x1);
    st4h(Xp + (size_t)Nc * DQ + off, x2);
    st4h(S3p + off, s3);
    st4h(QEp + off, qe);
}

// ---------------------------------------------------------------------------
// fp16 MFMA GEMM: Y = epi(act(A @ W^T + bias)), BM=BN=128, BK=32, 4 waves,
// wave tile 64x64 = 4x4 of v_mfma_f32_16x16x32_f16.
// MODE 1: tanh -> fp16 Yh (stride 128)               [lin1 on 2Nc rows]
// MODE 2: sig; row<Nc: tf->Yh; row>=Nc: x3=qe+v*s3 -> Yh  [lin2 batched]
// MODE 3: none; qp->Yh; fused ie=qp+tf*te -> AUX[,256:384] [lin1(X3)+ew_ie]
// MODE 4: gather A=qaE[idx]; by<2: sig->e, else tanh->a; packed u16 pairs->AUX
// MODE 5: tanh(rc); pred-partial reduce -> atomicAdd Yf    [readout+pred]
// ---------------------------------------------------------------------------
template <int MODE>
__global__ __launch_bounds__(256, 3) void gemm16(
    const u16* __restrict__ A, const u16* __restrict__ W0,
    const u16* __restrict__ W1, const float* __restrict__ b0,
    const float* __restrict__ b1, u16* __restrict__ Yh,
    float* __restrict__ Yf,
    const u16* __restrict__ QEp, const u16* __restrict__ S3p,
    const int* __restrict__ idx, const float* __restrict__ gtab,
    u16* __restrict__ AUX, const float* __restrict__ predW,
    int K, int Nc, int s0, int CS)
{
    __shared__ u16 smem[2 * 128 * 40];   // 20480 B: A-tile | B-tile (pitch 80B)
    u16* At = smem;
    u16* Bt = smem + 128 * 40;
    const int tid = threadIdx.x;
    const int row0 = blockIdx.x * 128;
    const int by = blockIdx.y;

    const u16* Wp;
    int col0;
    if constexpr (MODE == 4) { Wp = (by < 2) ? W0 : W1; col0 = (by & 1) * 128; }
    else { Wp = W0; col0 = by * 128; }
    const float* bias = (MODE == 4 && by >= 2) ? b1 : b0;

    floatx4 acc[4][4];
#pragma unroll
    for (int m = 0; m < 4; ++m)
#pragma unroll
        for (int n = 0; n < 4; ++n) acc[m][n] = (floatx4)0.f;

    const int lane = tid & 63, wv = tid >> 6;
    const int wr = (wv >> 1) * 64, wc = (wv & 1) * 64;
    const int q = lane >> 4, c0 = lane & 15;

    for (int kt = 0; kt < K; kt += 32) {
#pragma unroll
        for (int i = 0; i < 4; ++i) {
            int c = tid + i * 256;          // [0,1024)
            if (c < 512) {
                int r = c >> 2, seg = c & 3;
                const u16* src;
                if constexpr (MODE == 4) {
                    int g = idx[gmap(row0 + r, s0, CS)];
                    src = A + (size_t)g * K + kt + seg * 8;
                } else {
                    src = A + (size_t)(row0 + r) * K + kt + seg * 8;
                }
                *(uint4*)&At[r * 40 + seg * 8] = *(const uint4*)src;
            } else {
                int cb = c - 512;
                int r = cb >> 2, seg = cb & 3;
                const u16* src = Wp + (size_t)(col0 + r) * K + kt + seg * 8;
                *(uint4*)&Bt[r * 40 + seg * 8] = *(const uint4*)src;
            }
        }
        __syncthreads();
        half8 af[4], bf[4];
#pragma unroll
        for (int m = 0; m < 4; ++m) af[m] = *(half8*)&At[(wr + m * 16 + c0) * 40 + q * 8];
#pragma unroll
        for (int n = 0; n < 4; ++n) bf[n] = *(half8*)&Bt[(wc + n * 16 + c0) * 40 + q * 8];
#pragma unroll
        for (int m = 0; m < 4; ++m)
#pragma unroll
            for (int n = 0; n < 4; ++n)
                acc[m][n] = __builtin_amdgcn_mfma_f32_16x16x32_f16(af[m], bf[n], acc[m][n], 0, 0, 0);
        __syncthreads();
    }

    float bv[4];
#pragma unroll
    for (int n = 0; n < 4; ++n) bv[n] = bias[col0 + wc + n * 16 + c0];

    if constexpr (MODE == 5) {
        float pw[4];
#pragma unroll
        for (int n = 0; n < 4; ++n) pw[n] = predW[col0 + wc + n * 16 + c0];
        float* red = (float*)smem;          // [128][33] = 16896 B <= 20480
#pragma unroll
        for (int m = 0; m < 4; ++m)
#pragma unroll
            for (int r4 = 0; r4 < 4; ++r4) {
                int row = wr + m * 16 + q * 4 + r4;
                float pp = 0.f;
#pragma unroll
                for (int n = 0; n < 4; ++n)
                    pp = fmaf(tanhfast(acc[m][n][r4] + bv[n]), pw[n], pp);
                red[row * 33 + (wv & 1) * 16 + c0] = pp;
            }
        __syncthreads();
        if (tid < 128) {
            float s = 0.f;
#pragma unroll
            for (int j = 0; j < 32; ++j) s += red[tid * 33 + j];
            atomicAdd(&Yf[row0 + tid], s);
        }
    } else {
#pragma unroll
        for (int m = 0; m < 4; ++m)
#pragma unroll
            for (int r4 = 0; r4 < 4; ++r4) {
                int row = row0 + wr + m * 16 + q * 4 + r4;
#pragma unroll
                for (int n = 0; n < 4; ++n) {
                    int col = col0 + wc + n * 16 + c0;
                    float v = acc[m][n][r4] + bv[n];
                    if constexpr (MODE == 1) {
                        Yh[(size_t)row * 128 + col] = f2h(tanhfast(v));
                    } else if constexpr (MODE == 2) {
                        v = sigf(v);
                        if (row < Nc) {
                            Yh[(size_t)row * 128 + col] = f2h(v);
                        } else {
                            size_t o = (size_t)(row - Nc) * 128 + col;
                            float qe = h2f(QEp[o]), s3 = h2f(S3p[o]);
                            Yh[(size_t)row * 128 + col] = f2h(fmaf(v, s3, qe));
                        }
                    } else if constexpr (MODE == 3) {
                        size_t o = (size_t)row * 128 + col;
                        float tf = h2f(Yh[o]);   // read tf BEFORE overwriting with qp
                        float te = gtab[(size_t)idx[gmap(row, s0, CS)] * 128 + col];
                        AUX[(size_t)row * 384 + 256 + col] = f2h(fmaf(tf, te, v));
                        Yh[o] = f2h(v);
                    } else { // MODE 4
                        bool isE = (by < 2);
                        v = isE ? sigf(v) : tanhfast(v);
                        AUX[((size_t)row * 256 + col) * 2 + (isE ? 0 : 1)] = f2h(v);
                    }
                }
            }
    }
}

// ---------------------------------------------------------------------------
// w = softmax(qp @ Mk^T) via MFMA. Block: 128 rows x 64 cols (50 live).
// Logits -> LDS (pitch 67), row softmax, zero cols 50..63, coalesced store
// to Wb (stride WSTRIDE=64).
// ---------------------------------------------------------------------------
__global__ __launch_bounds__(256) void wsoftmax_mfma(
    const u16* __restrict__ QP, const u16* __restrict__ Mkh,
    float* __restrict__ Wb)
{
    __shared__ float Sred[128 * 67];        // 34304 B; head doubles as At/Bt
    u16* At = (u16*)Sred;                   // [128][40] fp16 = 10240 B
    u16* Bt = At + 128 * 40;                // [64][40]  fp16 =  5120 B
    const int tid = threadIdx.x;
    const int row0 = blockIdx.x * 128;
    const int lane = tid & 63, wv = tid >> 6;
    const int wr = wv * 32;                 // wave: 32 rows x 64 cols
    const int q = lane >> 4, c0 = lane & 15;

    floatx4 acc[2][4];
#pragma unroll
    for (int m = 0; m < 2; ++m)
#pragma unroll
        for (int n = 0; n < 4; ++n) acc[m][n] = (floatx4)0.f;

    for (int kt = 0; kt < DQ; kt += 32) {
#pragma unroll
        for (int i = 0; i < 3; ++i) {
            int c = tid + i * 256;          // [0,768)
            if (c < 512) {
                int r = c >> 2, seg = c & 3;
                *(uint4*)&At[r * 40 + seg * 8] =
                    *(const uint4*)(QP + (size_t)(row0 + r) * DQ + kt + seg * 8);
            } else {
                int cb = c - 512;
                int r = cb >> 2, seg = cb & 3;
                *(uint4*)&Bt[r * 40 + seg * 8] =
                    *(const uint4*)(Mkh + (size_t)r * DQ + kt + seg * 8);
            }
        }
        __syncthreads();
        half8 af[2], bf[4];
#pragma unroll
        for (int m = 0; m < 2; ++m) af[m] = *(half8*)&At[(wr + m * 16 + c0) * 40 + q * 8];
#pragma unroll
        for (int n = 0; n < 4; ++n) bf[n] = *(half8*)&Bt[(n * 16 + c0) * 40 + q * 8];
#pragma unroll
        for (int m = 0; m < 2; ++m)
#pragma unroll
            for (int n = 0; n < 4; ++n)
                acc[m][n] = __builtin_amdgcn_mfma_f32_16x16x32_f16(af[m], bf[n], acc[m][n], 0, 0, 0);
        __syncthreads();
    }

    // dump logits to LDS: row = wr + m*16 + q*4 + r, col = n*16 + c0
#pragma unroll
    for (int m = 0; m < 2; ++m)
#pragma unroll
        for (int r4 = 0; r4 < 4; ++r4) {
            int row = wr + m * 16 + q * 4 + r4;
#pragma unroll
            for (int n = 0; n < 4; ++n)
                Sred[row * 67 + n * 16 + c0] = acc[m][n][r4];
        }
    __syncthreads();

    // row-wise softmax over 50 live cols; zero pad cols 50..63
    if (tid < 128) {
        float* s = &Sred[tid * 67];
        float mx = -3.0e38f;
#pragma unroll
        for (int m = 0; m < MM; ++m) mx = fmaxf(mx, s[m]);
        float sum = 0.f;
#pragma unroll
        for (int m = 0; m < MM; ++m) { float e = __expf(s[m] - mx); s[m] = e; sum += e; }
        float inv = 1.f / sum;
#pragma unroll
        for (int m = 0; m < MM; ++m) s[m] *= inv;
#pragma unroll
        for (int m = MM; m < 64; ++m) s[m] = 0.f;
    }
    __syncthreads();

    // coalesced store: 128 rows x 16 float4
    for (int i = tid; i < 128 * 16; i += 256) {
        int row = i >> 4, seg = i & 15;
        float4 v;
        v.x = Sred[row * 67 + seg * 4 + 0];
        v.y = Sred[row * 67 + seg * 4 + 1];
        v.z = Sred[row * 67 + seg * 4 + 2];
        v.w = Sred[row * 67 + seg * 4 + 3];
        *(float4*)(Wb + (size_t)(row0 + row) * WSTRIDE + seg * 4) = v;
    }
}

// ---------------------------------------------------------------------------
// DKVMN scan v6: 512 blocks (batch x d-half) x 1024 threads.
// m-split 8-way (wave = 8 d x 8 mg); mv[8] in two named float4s; w + e/a in
// double-buffered LDS tiles. NO per-step reduction: each thread writes its
// 8-wide dot partial to an LDS slab Pt[s][mg*132+dloc] (conflict-free), and
// a tile-end cooperative pass sums 8 partials per (s,d) and stores RDIE
// coalesced. Update uses the 2-FMA form mv = fmaf(-w, fmaf(e,mv,-a), mv).
// ---------------------------------------------------------------------------
__device__ __forceinline__ float dot8(
    const float4& w0, const float4& w1, const float4& m0, const float4& m1)
{
    float r = w0.x * m0.x;
    r = fmaf(w0.y, m0.y, r); r = fmaf(w0.z, m0.z, r); r = fmaf(w0.w, m0.w, r);
    r = fmaf(w1.x, m1.x, r); r = fmaf(w1.y, m1.y, r); r = fmaf(w1.z, m1.z, r); r = fmaf(w1.w, m1.w, r);
    return r;
}

__device__ __forceinline__ void upd2(float4& mv, const float4& wv, float e, float a)
{
    mv.x = fmaf(-wv.x, fmaf(e, mv.x, -a), mv.x);
    mv.y = fmaf(-wv.y, fmaf(e, mv.y, -a), mv.y);
    mv.z = fmaf(-wv.z, fmaf(e, mv.z, -a), mv.z);
    mv.w = fmaf(-wv.w, fmaf(e, mv.w, -a), mv.w);
}

__global__ __launch_bounds__(1024, 2) void scan_kernel(
    const float* __restrict__ Wb, const u32* __restrict__ EA,
    const float* __restrict__ Mv0, float* __restrict__ MvSt,
    u16* __restrict__ RDIE, int CS, int first)
{
    __shared__ float wt[2][STILE * 64];     // 2 x 2560 B
    __shared__ u32  eat[2][STILE * 128];    // 2 x 5120 B
    __shared__ float Pt[STILE * 1056];      // 42240 B: [s][mg*132 + dloc]
    const int bb = blockIdx.x >> 1;
    const int dh = blockIdx.x & 1;
    const int tid = threadIdx.x;
    const int lane = tid & 63;
    const int wave = tid >> 6;
    const int mg = lane >> 3;          // 0..7
    const int dl = lane & 7;
    const int dloc = wave * 8 + dl;    // 0..127
    const int d = dh * 128 + dloc;     // 0..255
    const int m0 = mg * 8;

    float4 mv0, mv1;
    {
        float t0[8];
#pragma unroll
        for (int j = 0; j < 8; ++j) {
            int m = m0 + j;
            t0[j] = (m < MM) ? (first ? Mv0[m * DV + d]
                                      : MvSt[((size_t)bb * MM + m) * DV + d]) : 0.f;
        }
        mv0 = float4{t0[0], t0[1], t0[2], t0[3]};
        mv1 = float4{t0[4], t0[5], t0[6], t0[7]};
    }

    const float* wbase = Wb + (size_t)bb * CS * WSTRIDE;
    const u32* ebase = EA + (size_t)bb * CS * DV + dh * 128;
    u16* rbase = RDIE + ((size_t)bb * CS) * 384 + dh * 128;

    const int NT = (CS + STILE - 1) / STILE;
    const bool wload = (tid < STILE * 16);                      // 160 float4 loaders
    const bool eload = (tid >= 256 && tid < 256 + STILE * 32);  // 320 uint4 loaders
    const int wj = tid;
    const int ej = tid - 256;
    const int es = eload ? (ej >> 5) : 0;
    const int ec = eload ? (ej & 31) : 0;

    // Preload tile 0
    if (wload) *(float4*)&wt[0][wj * 4] = ld4(wbase + wj * 4);
    if (eload) *(uint4*)&eat[0][es * 128 + ec * 4] =
        *(const uint4*)(ebase + (size_t)es * DV + ec * 4);
    __syncthreads();

    int cur = 0;
    for (int tile = 0; tile < NT; ++tile) {
        const int base = tile * STILE;
        const int nst = (CS - base < STILE) ? (CS - base) : STILE;
        const bool have = (tile + 1 < NT);

        // Prefetch next tile into regs (overlaps compute; buffers padded)
        float4 wv{0.f, 0.f, 0.f, 0.f};
        uint4 ev{0, 0, 0, 0};
        if (have) {
            if (wload) wv = ld4(wbase + (size_t)(base + STILE) * WSTRIDE + wj * 4);
            if (eload) ev = *(const uint4*)(ebase + (size_t)(base + STILE + es) * DV + ec * 4);
        }

        const float* wcur = wt[cur];
        const u32* ecur = eat[cur];
        float* pout = &Pt[mg * 132 + dloc];

        if (nst == STILE) {
#pragma unroll
            for (int s = 0; s < STILE; ++s) {
                float4 w0 = *(const float4*)&wcur[s * 64 + m0];
                float4 w1 = *(const float4*)&wcur[s * 64 + m0 + 4];
                u32 eav = ecur[s * 128 + dloc];
                const float e = h2f((u16)(eav & 0xffff));
                const float a = h2f((u16)(eav >> 16));
                pout[s * 1056] = dot8(w0, w1, mv0, mv1);
                upd2(mv0, w0, e, a);
                upd2(mv1, w1, e, a);
            }
        } else {
            for (int s = 0; s < nst; ++s) {
                float4 w0 = *(const float4*)&wcur[s * 64 + m0];
                float4 w1 = *(const float4*)&wcur[s * 64 + m0 + 4];
                u32 eav = ecur[s * 128 + dloc];
                const float e = h2f((u16)(eav & 0xffff));
                const float a = h2f((u16)(eav >> 16));
                pout[s * 1056] = dot8(w0, w1, mv0, mv1);
                upd2(mv0, w0, e, a);
                upd2(mv1, w1, e, a);
            }
        }
        __syncthreads();   // Pt complete

        // Tile-end reduce: sum 8 partials per (s, dloc) -> coalesced RDIE
        for (int i = tid; i < nst * 128; i += 1024) {
            int s = i >> 7, dd = i & 127;
            float sum = 0.f;
#pragma unroll
            for (int g = 0; g < 8; ++g) sum += Pt[s * 1056 + g * 132 + dd];
            rbase[(size_t)(base + s) * 384 + dd] = f2h(sum);
        }

        if (have) {
            if (wload) *(float4*)&wt[1 - cur][wj * 4] = wv;
            if (eload) *(uint4*)&eat[1 - cur][es * 128 + ec * 4] = ev;
        }
        __syncthreads();   // Pt consumed + next tile staged
        if (have) cur ^= 1;
    }

    {
        float sv[8] = {mv0.x, mv0.y, mv0.z, mv0.w, mv1.x, mv1.y, mv1.z, mv1.w};
#pragma unroll
        for (int j = 0; j < 8; ++j) {
            int m = m0 + j;
            if (m < MM) MvSt[((size_t)bb * MM + m) * DV + d] = sv[j];
        }
    }
}

// ---------------------------------------------------------------------------
// loss + outputs
// ---------------------------------------------------------------------------
__global__ __launch_bounds__(256) void loss_part(
    const float* __restrict__ P, const int* __restrict__ target,
    const float* __restrict__ pred_b, float* __restrict__ out,
    float* __restrict__ R2, int s0, int CS, int Nc)
{
    int l = blockIdx.x * 256 + threadIdx.x;
    float le = 0.f, mf = 0.f;
    if (l < Nc) {
        int n = gmap(l, s0, CS);
        float p = P[l] + pred_b[0];
        int t = target[n];
        float y = (t >= 1) ? (float)(t - 1) : 0.f;
        float sig = 1.f / (1.f + __expf(-p));
        if (t >= 1) {
            mf = 1.f;
            le = fmaxf(p, 0.f) + log1pf(__expf(-fabsf(p))) - p * y;
        }
        out[1 + n] = sig * mf;
        out[1 + NROWS + n] = y * mf;
    }
#pragma unroll
    for (int off = 32; off; off >>= 1) {
        le += __shfl_down(le, off);
        mf += __shfl_down(mf, off);
    }
    __shared__ float sl[4], sm[4];
    int wid = threadIdx.x >> 6;
    if ((threadIdx.x & 63) == 0) { sl[wid] = le; sm[wid] = mf; }
    __syncthreads();
    if (threadIdx.x == 0) {
        atomicAdd(R2, sl[0] + sl[1] + sl[2] + sl[3]);
        atomicAdd(R2 + 1, sm[0] + sm[1] + sm[2] + sm[3]);
    }
}

__global__ void loss_fin(const float* __restrict__ R2, float* __restrict__ out)
{
    out[0] = R2[0] / fmaxf(R2[1], 1.f);
}

// ---------------------------------------------------------------------------
extern "C" void kernel_launch(void* const* d_in, const int* in_sizes, int n_in,
                              void* d_out, int out_size, void* d_ws, size_t ws_size,
                              hipStream_t stream)
{
    const int* q_data       = (const int*)d_in[0];
    const int* qa_data      = (const int*)d_in[1];
    const int* target       = (const int*)d_in[2];
    const int* time_data    = (const int*)d_in[3];
    const int* attempt_data = (const int*)d_in[4];
    const int* hint_data    = (const int*)d_in[5];
    const int* hintT_data   = (const int*)d_in[6];
    const float* q_emb    = (const float*)d_in[7];
    const float* qa_emb   = (const float*)d_in[8];
    const float* time_emb = (const float*)d_in[9];
    const float* att_emb  = (const float*)d_in[10];
    const float* ht_emb   = (const float*)d_in[11];
    const float* Mk       = (const float*)d_in[12];
    const float* Mv0      = (const float*)d_in[13];
    const float* diff_W   = (const float*)d_in[14];
    const float* diff_b   = (const float*)d_in[15];
    const float* diff2_W  = (const float*)d_in[16];
    const float* diff2_b  = (const float*)d_in[17];
    const float* erase_W  = (const float*)d_in[18];
    const float* erase_b  = (const float*)d_in[19];
    const float* add_W    = (const float*)d_in[20];
    const float* add_b    = (const float*)d_in[21];
    const float* read_W   = (const float*)d_in[22];
    const float* read_b   = (const float*)d_in[23];
    const float* pred_W   = (const float*)d_in[24];
    const float* pred_b   = (const float*)d_in[25];
    float* out = (float*)d_out;
    (void)in_sizes; (void)n_in; (void)out_size;

    // Adaptive chunking over S.
    static const int cs_opts[] = {500, 250, 125, 100, 50, 25, 20, 10, 5, 4, 2};
    const size_t FIXED = 24200000ull;
    int CS = 0;
    for (int i = 0; i < 11; ++i) {
        size_t need = (size_t)NB * cs_opts[i] * 3080ull + FIXED;
        if (need <= ws_size) { CS = cs_opts[i]; break; }
    }
    if (CS == 0) return;
    const int NCH = SQ / CS;
    const int Nc = NB * CS;

    // Workspace layout (16B-aligned sections; wbuf/EAu padded by STILE rows)
    float* MvSt  = (float*)d_ws;                         // [NB*MM*DV]
    float* wbuf  = MvSt + (size_t)NB * MM * DV;          // [Nc*64 + pad]
    float* bufP  = wbuf + (size_t)Nc * WSTRIDE + STILE * WSTRIDE;   // [Nc]
    float* bufR2 = bufP + Nc;                            // [4]
    u32*  EAu    = (u32*)(bufR2 + 4);                    // [Nc*256 + pad]
    u16*  Xp     = (u16*)(EAu + (size_t)Nc * 256 + STILE * 256);    // [2Nc*128]
    u16*  S3p    = Xp + (size_t)2 * Nc * 128;            // [Nc*128]
    u16*  QEp    = S3p + (size_t)Nc * 128;               // [Nc*128]
    u16*  RDIE   = QEp + (size_t)Nc * 128;               // [Nc*384]
    u16*  dWh    = RDIE + (size_t)Nc * 384;              // 16384
    u16*  d2Wh   = dWh + 16384;                          // 16384
    u16*  eWh    = d2Wh + 16384;                         // 65536
    u16*  aWh    = eWh + 65536;                          // 65536
    u16*  rWh    = aWh + 65536;                          // 196608
    u16*  qaEh   = rWh + 196608;                         // 5,120,256
    u16*  Mkh    = qaEh + 5120256;                       // 8,192 (64x128)

    // One-time weight/table conversions to fp16
    cvt16<<<16, 256, 0, stream>>>(diff_W,  dWh,  16384 / 4);
    cvt16<<<16, 256, 0, stream>>>(diff2_W, d2Wh, 16384 / 4);
    cvt16<<<64, 256, 0, stream>>>(erase_W, eWh,  65536 / 4);
    cvt16<<<64, 256, 0, stream>>>(add_W,   aWh,  65536 / 4);
    cvt16<<<192, 256, 0, stream>>>(read_W, rWh,  196608 / 4);
    cvt16<<<5001, 256, 0, stream>>>(qa_emb, qaEh, 5120256 / 4);
    mkcvt<<<8, 256, 0, stream>>>(Mk, Mkh);
    hipMemsetAsync(bufR2, 0, 4 * sizeof(float), stream);

    for (int c = 0; c < NCH; ++c) {
        const int s0 = c * CS;

        prep128<<<Nc / 8, 256, 0, stream>>>(
            q_data, time_data, attempt_data, hint_data, hintT_data,
            q_emb, time_emb, att_emb, ht_emb, Xp, S3p, QEp, s0, CS, Nc);

        // G1: [T1;T2] = tanh(lin1([X1;X2]))  (in-place Xp, 2Nc rows)
        gemm16<1><<<dim3(2 * Nc / 128, 1), 256, 0, stream>>>(
            Xp, dWh, nullptr, diff_b, nullptr, Xp, nullptr,
            nullptr, nullptr, nullptr, nullptr, nullptr, nullptr, 128, Nc, s0, CS);
        // G2: sig(lin2): rows<Nc -> tf; rows>=Nc -> x3 = qe + df*s3  (in-place)
        gemm16<2><<<dim3(2 * Nc / 128, 1), 256, 0, stream>>>(
            Xp, d2Wh, nullptr, diff2_b, nullptr, Xp, nullptr,
            QEp, S3p, nullptr, nullptr, nullptr, nullptr, 128, Nc, s0, CS);
        // G3: qp = lin1(x3) -> Xp[0:Nc); fused ie = qp + tf*te -> RDIE[:,256:)
        gemm16<3><<<dim3(Nc / 128, 1), 256, 0, stream>>>(
            Xp + (size_t)Nc * 128, dWh, nullptr, diff_b, nullptr, Xp, nullptr,
            nullptr, nullptr, time_data, time_emb, RDIE, nullptr, 128, Nc, s0, CS);
        // w = softmax(qp @ Mk^T) via MFMA
        wsoftmax_mfma<<<Nc / 128, 256, 0, stream>>>(Xp, Mkh, wbuf);
        // G4: e/a gates, gather-A from fp16 qa_emb, packed (e,a) -> EAu
        gemm16<4><<<dim3(Nc / 128, 4), 256, 0, stream>>>(
            qaEh, eWh, aWh, erase_b, add_b, nullptr, nullptr,
            nullptr, nullptr, qa_data, nullptr, (u16*)EAu, nullptr, 256, Nc, s0, CS);
        // scan v6 -> RD fp16 into RDIE[:,0:256)
        scan_kernel<<<NB * 2, 1024, 0, stream>>>(wbuf, EAu, Mv0, MvSt, RDIE, CS, c == 0 ? 1 : 0);

        hipMemsetAsync(bufP, 0, (size_t)Nc * sizeof(float), stream);
        // G5: rc = tanh([rd|ie] @ read_W^T + b); pred partials -> bufP
        gemm16<5><<<dim3(Nc / 128, 4), 256, 0, stream>>>(
            RDIE, rWh, nullptr, read_b, nullptr, nullptr, bufP,
            nullptr, nullptr, nullptr, nullptr, nullptr, pred_W, 384, Nc, s0, CS);

        loss_part<<<Nc / 256, 256, 0, stream>>>(bufP, target, pred_b, out, bufR2, s0, CS, Nc);
    }

    loss_fin<<<1, 1, 0, stream>>>(bufR2, out);
}